// Round 20
// baseline (184.634 us; speedup 1.0000x reference)
//
#include <hip/hip_runtime.h>
#include <hip/hip_bf16.h>

#define NOBJ 25
#define CONV_REP 16
#define MLP_REP 32

typedef _Float16 f16x8 __attribute__((ext_vector_type(8)));
typedef short s16x4 __attribute__((ext_vector_type(4)));
typedef float f32x4 __attribute__((ext_vector_type(4)));
typedef unsigned int uint;

__device__ __forceinline__ short f2h_s(float f) {
  _Float16 h = (_Float16)f;   // single v_cvt_f16_f32 (RTN)
  return *reinterpret_cast<short*>(&h);
}

// ===========================================================================
// DIAGNOSTIC ROUND 3: exact R19 kernels (27.9us config) with internal repeat
// loops so both dispatches clear the ~39us fill cutoff and produce counter
// rows. Repeats recompute identical values (deterministic).
// ===========================================================================

// ---------------------------------------------------------------------------
// K1 (R19 + rep loop): 512 blocks; per block: inline prep share + conv for
// samples 2*bid, 2*bid+1. f16 MFMA path.
// ---------------------------------------------------------------------------
__global__ __launch_bounds__(256, 2) void conv_prep_kernel(
    const float* __restrict__ x,    // (1024, 25*64)
    const float* __restrict__ cw0,  // (256, 64)
    const float* __restrict__ cw1,  // (256, 64)
    const float* __restrict__ cb,   // (256)
    const float* __restrict__ w1, const float* __restrict__ w2,
    const float* __restrict__ w3,
    short* __restrict__ h0,         // (1024, 256) f16 bits
    short* __restrict__ wfm)        // 135168 shorts, fragment-linear f16
{
  __shared__ short xs[2][32][72];        // 9216 B (f16 bits)
  __shared__ float ab[4][2][NOBJ][68];   // 54400 B (per-wave scratch)

  const int t = threadIdx.x;
  const int lane = t & 63;
  const int wv = t >> 6;
  const int r = lane & 15;
  const int g = lane >> 4;
  const int n0 = blockIdx.x * 2;

  // one-time: conv W fragments (registers persist across reps)
  f16x8 Wf[2][4][2];  // [tap][ntile][kstep]
#pragma unroll
  for (int tap = 0; tap < 2; ++tap) {
    const float* wsrc = tap ? cw1 : cw0;
#pragma unroll
    for (int ntl = 0; ntl < 4; ++ntl)
#pragma unroll
      for (int ks = 0; ks < 2; ++ks) {
        const int ch = wv * 64 + ntl * 16 + r;
        const float* p = wsrc + ch * 64 + ks * 32 + g * 8;
        const float4 a = *reinterpret_cast<const float4*>(p);
        const float4 b = *reinterpret_cast<const float4*>(p + 4);
        f16x8 fr;
        fr[0] = (_Float16)a.x; fr[1] = (_Float16)a.y; fr[2] = (_Float16)a.z; fr[3] = (_Float16)a.w;
        fr[4] = (_Float16)b.x; fr[5] = (_Float16)b.y; fr[6] = (_Float16)b.z; fr[7] = (_Float16)b.w;
        Wf[tap][ntl][ks] = fr;
      }
  }
  float cbv[4];
#pragma unroll
  for (int ntl = 0; ntl < 4; ++ntl) cbv[ntl] = cb[wv * 64 + ntl * 16 + r];

#pragma unroll 1
  for (int rep = 0; rep < CONV_REP; ++rep) {
    __syncthreads();  // protect xs against prior rep's readers

    // x staging
    for (int s = 0; s < 2; ++s) {
      const float4* xg = reinterpret_cast<const float4*>(x + (size_t)(n0 + s) * (NOBJ * 64));
      for (int i = t; i < 400; i += 256) {
        float4 v = xg[i];
        s16x4 p;
        p.x = f2h_s(v.x); p.y = f2h_s(v.y); p.z = f2h_s(v.z); p.w = f2h_s(v.w);
        *reinterpret_cast<s16x4*>(&xs[s][i >> 4][(i & 15) * 4]) = p;
      }
    }

    // inline prep share (single f16, fragment-linear)
    for (int j = blockIdx.x * 256 + t; j < 135168; j += 512 * 256) {
      const float* w; int f, nt;
      const bool isw3 = (j >= 131072);
      if (!isw3) {
        w = (j >> 16) ? w2 : w1;
        f = j & 65535;
        nt = f >> 12;
      } else {
        f = j - 131072;  // 0..4095
        w = w3;
        nt = 0;
      }
      const int ks = (f >> 9) & 7;
      const int l  = (f >> 3) & 63;
      const int jj = f & 7;
      const int col = nt * 16 + (l & 15);
      const int k   = ks * 32 + (l >> 4) * 8 + jj;
      const float v = (isw3 && col >= 10) ? 0.f : w[col * 256 + k];
      wfm[j] = f2h_s(v);
    }

    __syncthreads();

    for (int s = 0; s < 2; ++s) {
      f16x8 Xf[2][2];  // rows 25..31 garbage, outputs unread
#pragma unroll
      for (int mt = 0; mt < 2; ++mt)
#pragma unroll
        for (int ks = 0; ks < 2; ++ks)
          Xf[mt][ks] = *reinterpret_cast<const f16x8*>(&xs[s][mt * 16 + r][ks * 32 + g * 8]);

      f32x4 acc[2][2][4];  // [tap][mtile][ntile]
#pragma unroll
      for (int tap = 0; tap < 2; ++tap)
#pragma unroll
        for (int mt = 0; mt < 2; ++mt)
#pragma unroll
          for (int ntl = 0; ntl < 4; ++ntl) {
            f32x4 z = {0.f, 0.f, 0.f, 0.f};
            acc[tap][mt][ntl] = z;
          }

#pragma unroll
      for (int tap = 0; tap < 2; ++tap)
#pragma unroll
        for (int mt = 0; mt < 2; ++mt)
#pragma unroll
          for (int ntl = 0; ntl < 4; ++ntl)
#pragma unroll
            for (int ks = 0; ks < 2; ++ks)
              acc[tap][mt][ntl] = __builtin_amdgcn_mfma_f32_16x16x32_f16(
                  Xf[mt][ks], Wf[tap][ntl][ks], acc[tap][mt][ntl], 0, 0, 0);

#pragma unroll
      for (int tap = 0; tap < 2; ++tap)
#pragma unroll
        for (int mt = 0; mt < 2; ++mt)
#pragma unroll
          for (int ntl = 0; ntl < 4; ++ntl) {
            const int cl = ntl * 16 + r;
            const int row0 = mt * 16 + g * 4;
            const float badd = (tap == 0) ? cbv[ntl] : 0.f;
#pragma unroll
            for (int q = 0; q < 4; ++q)
              if (row0 + q < NOBJ) ab[wv][tap][row0 + q][cl] = acc[tap][mt][ntl][q] + badd;
          }
      // same-wave LDS RAW ordered by lgkmcnt; ab wave-private -> no barrier

      float A[NOBJ], Bv[NOBJ];
#pragma unroll
      for (int i = 0; i < NOBJ; ++i) { A[i] = ab[wv][0][i][lane]; Bv[i] = ab[wv][1][i][lane]; }
      float hacc = 0.f;
#pragma unroll
      for (int d = 1; d < NOBJ; ++d) {
        float sd = 0.f;
#pragma unroll
        for (int i = 0; i + d < NOBJ; ++i) sd += fmaxf(A[i] + Bv[i + d], 0.f);
        hacc = __builtin_fmaf(sd, 1.0f / (float)(NOBJ - d), hacc);
      }
      h0[(size_t)(n0 + s) * 256 + t] = f2h_s(hacc * (1.0f / (float)(NOBJ - 1)));
    }
  }
}

// ---------------------------------------------------------------------------
// K2 (R19 + rep loop): full 3-layer MLP, single f16, 64 blocks x 1024 thr.
// ---------------------------------------------------------------------------
__global__ __launch_bounds__(1024, 4) void mlp_fused(
    const short* __restrict__ h0,   // (1024,256) f16 bits
    const short* __restrict__ wfm,  // fragment-linear f16 weights
    const float* __restrict__ b1, const float* __restrict__ b2,
    const float* __restrict__ b3,
    float* __restrict__ out)        // (1024, 10)
{
  __shared__ short Hs[2][16][272];  // [pp][row][k] f16 bits, 17408 B
  const int t = threadIdx.x, lane = t & 63, wv = t >> 6;
  const int r = lane & 15, g = lane >> 4;
  const int m0 = blockIdx.x * 16;

#pragma unroll 1
  for (int rep = 0; rep < MLP_REP; ++rep) {
    __syncthreads();  // protect Hs against prior rep's readers
    {
      const s16x4 v = reinterpret_cast<const s16x4*>(h0 + (size_t)m0 * 256)[t];
      *reinterpret_cast<s16x4*>(&Hs[0][t >> 6][(t & 63) * 4]) = v;
    }
    __syncthreads();

    int pp = 0;
    const float* bias[2] = {b1, b2};
#pragma unroll
    for (int L = 0; L < 2; ++L) {
      const short* wl = wfm + L * 65536;

      f16x8 bfr[8];
#pragma unroll
      for (int ks = 0; ks < 8; ++ks)
        bfr[ks] = *reinterpret_cast<const f16x8*>(wl + ((wv * 8 + ks) << 9) + lane * 8);

      const float bv = bias[L][wv * 16 + r];
      f32x4 acc = {bv, bv, bv, bv};
#pragma unroll
      for (int ks = 0; ks < 8; ++ks) {
        const f16x8 afr = *reinterpret_cast<const f16x8*>(&Hs[pp][r][ks * 32 + g * 8]);
        acc = __builtin_amdgcn_mfma_f32_16x16x32_f16(afr, bfr[ks], acc, 0, 0, 0);
      }

      const int col = wv * 16 + r;
#pragma unroll
      for (int q = 0; q < 4; ++q)
        Hs[pp ^ 1][4 * g + q][col] = f2h_s(fmaxf(acc[q], 0.f));
      __syncthreads();
      pp ^= 1;
    }

    // layer 3: one 16x16 tile (cols 10..15 zero-padded), wave 0 only
    if (wv == 0) {
      const float bv = (r < 10) ? b3[r] : 0.f;
      f32x4 acc = {bv, bv, bv, bv};
#pragma unroll
      for (int ks = 0; ks < 8; ++ks) {
        const f16x8 afr = *reinterpret_cast<const f16x8*>(&Hs[pp][r][ks * 32 + g * 8]);
        const f16x8 bfr = *reinterpret_cast<const f16x8*>(wfm + 131072 + (ks << 9) + lane * 8);
        acc = __builtin_amdgcn_mfma_f32_16x16x32_f16(afr, bfr, acc, 0, 0, 0);
      }
      if (r < 10) {
#pragma unroll
        for (int q = 0; q < 4; ++q)
          out[(size_t)(m0 + 4 * g + q) * 10 + r] = acc[q];
      }
    }
  }
}

extern "C" void kernel_launch(void* const* d_in, const int* in_sizes, int n_in,
                              void* d_out, int out_size, void* d_ws, size_t ws_size,
                              hipStream_t stream) {
  const float* x   = (const float*)d_in[0];
  const float* cw0 = (const float*)d_in[1];
  const float* cw1 = (const float*)d_in[2];
  const float* cb  = (const float*)d_in[3];
  const float* w1  = (const float*)d_in[4];
  const float* b1  = (const float*)d_in[5];
  const float* w2  = (const float*)d_in[6];
  const float* b2  = (const float*)d_in[7];
  const float* w3  = (const float*)d_in[8];
  const float* b3  = (const float*)d_in[9];
  float* out = (float*)d_out;

  short* h0  = (short*)d_ws;           // 512 KB f16
  short* wfm = h0 + 262144;            // 264 KB f16 frag-linear weights

  conv_prep_kernel<<<512, 256, 0, stream>>>(x, cw0, cw1, cb, w1, w2, w3, h0, wfm);
  mlp_fused<<<64, 1024, 0, stream>>>(h0, wfm, b1, b2, b3, out);
}

// Round 21
// 29.662 us; speedup vs baseline: 6.2246x; 6.2246x over previous
//
#include <hip/hip_runtime.h>
#include <hip/hip_bf16.h>

#define NOBJ 25

typedef _Float16 f16x8 __attribute__((ext_vector_type(8)));
typedef _Float16 f16x2 __attribute__((ext_vector_type(2)));
typedef short s16x4 __attribute__((ext_vector_type(4)));
typedef float f32x4 __attribute__((ext_vector_type(4)));
typedef unsigned int uint;

__device__ __forceinline__ short f2h_s(float f) {
  _Float16 h = (_Float16)f;   // single v_cvt_f16_f32 (RTN)
  return *reinterpret_cast<short*>(&h);
}
__device__ __forceinline__ f16x8 cvt8h(const float* p) {
  const float4 a = *reinterpret_cast<const float4*>(p);
  const float4 b = *reinterpret_cast<const float4*>(p + 4);
  f16x8 fr;
  fr[0] = (_Float16)a.x; fr[1] = (_Float16)a.y; fr[2] = (_Float16)a.z; fr[3] = (_Float16)a.w;
  fr[4] = (_Float16)b.x; fr[5] = (_Float16)b.y; fr[6] = (_Float16)b.z; fr[7] = (_Float16)b.w;
  return fr;
}
__device__ __forceinline__ f16x2 pk_max(f16x2 a, f16x2 b) {
  f16x2 r;
  asm("v_pk_max_f16 %0, %1, %2" : "=v"(r) : "v"(a), "v"(b));
  return r;
}

// ---------------------------------------------------------------------------
// K1: 1024 blocks x 256 thr (4 waves), 4 blocks/CU (LDS 27.5KB, VGPR<=128 via
// launch_bounds(256,4)) -> 4 waves/SIMD TLP (2x R19/20's 2).
// Block cbid: samples n0=(cbid>>1)*2, n0+1; channels (cbid&1)*128 + wv*32.
// Per wave (32 channels, both samples):
//  - Wf f16 frags inline; Xf DIRECT from global (L1-shared; rows>24 clamp).
//  - per sample: 16 MFMAs -> scatter f16 halves into packed ab
//    (ab[tap][obj][chan][sample] shorts; uint read = (s0,s1) f16 pair);
//    tap1 row 25 = -6e4 pad (relu kills it).
//  - PACKED pairwise: lane = (dhalf h = lane>>5, chan c = lane&31);
//    h folded into the B LDS-load shift (register indices all static);
//    per term: pk_add + pk_max + pk_add (3 instr for both samples);
//    sd f16x2 -> f32 per-d weighted fma; halves combined via shfl_xor(32).
//  - prep share grid-strided (<=1 elem/thread), f16 fragment-linear.
// ---------------------------------------------------------------------------
__global__ __launch_bounds__(256, 4) void conv_prep_kernel(
    const float* __restrict__ x,    // (1024, 25*64)
    const float* __restrict__ cw0,  // (256, 64)
    const float* __restrict__ cw1,  // (256, 64)
    const float* __restrict__ cb,   // (256)
    const float* __restrict__ w1, const float* __restrict__ w2,
    const float* __restrict__ w3,
    short* __restrict__ h0,         // (1024, 256) f16 bits
    short* __restrict__ wfm)        // 135168 shorts, fragment-linear f16
{
  __shared__ short abp[4][2][26][33][2];  // [wave][tap][obj(+pad)][chan][sample] 27456B

  const int t = threadIdx.x;
  const int lane = t & 63;
  const int wv = t >> 6;
  const int r = lane & 15;
  const int g = lane >> 4;
  const int cbid = blockIdx.x;
  const int n0 = (cbid >> 1) * 2;
  const int chbase = (cbid & 1) * 128 + wv * 32;

  // ---- prep share (grid-strided over 1024*256 threads) ----
  for (int j = cbid * 256 + t; j < 135168; j += 1024 * 256) {
    const float* w; int f, nt;
    const bool isw3 = (j >= 131072);
    if (!isw3) {
      w = (j >> 16) ? w2 : w1;
      f = j & 65535;
      nt = f >> 12;
    } else {
      f = j - 131072;  // 0..4095
      w = w3;
      nt = 0;
    }
    const int ks = (f >> 9) & 7;
    const int l  = (f >> 3) & 63;
    const int jj = f & 7;
    const int col = nt * 16 + (l & 15);
    const int k   = ks * 32 + (l >> 4) * 8 + jj;
    const float v = (isw3 && col >= 10) ? 0.f : w[col * 256 + k];
    wfm[j] = f2h_s(v);
  }

  // ---- W fragments: 32 channels (2 ntl), both taps ----
  f16x8 Wf[2][2][2];  // [tap][ntl][ks]
#pragma unroll
  for (int tap = 0; tap < 2; ++tap) {
    const float* wsrc = tap ? cw1 : cw0;
#pragma unroll
    for (int ntl = 0; ntl < 2; ++ntl)
#pragma unroll
      for (int ks = 0; ks < 2; ++ks)
        Wf[tap][ntl][ks] = cvt8h(wsrc + (chbase + ntl * 16 + r) * 64 + ks * 32 + g * 8);
  }
  float cbv[2];
#pragma unroll
  for (int ntl = 0; ntl < 2; ++ntl) cbv[ntl] = cb[chbase + ntl * 16 + r];

  // tap1 pad row 25 = -6e4 (relu-dead); wave-private, same-wave ordering
  if (g == 0) {
#pragma unroll
    for (int ntl = 0; ntl < 2; ++ntl) {
      abp[wv][1][25][ntl * 16 + r][0] = f2h_s(-6.0e4f);
      abp[wv][1][25][ntl * 16 + r][1] = f2h_s(-6.0e4f);
    }
  }

  // ---- per sample: MFMA + f16-half scatter ----
#pragma unroll
  for (int s = 0; s < 2; ++s) {
    const int n = n0 + s;
    f16x8 Xf[2][2];  // [mt][ks]; rows>24 clamp to 24 (outputs unread)
#pragma unroll
    for (int mt = 0; mt < 2; ++mt) {
      const int row = mt * 16 + r;
      const int rowc = row > 24 ? 24 : row;
#pragma unroll
      for (int ks = 0; ks < 2; ++ks)
        Xf[mt][ks] = cvt8h(x + (size_t)n * 1600 + rowc * 64 + ks * 32 + g * 8);
    }

    f32x4 acc[2][2][2];  // [tap][mt][ntl]
#pragma unroll
    for (int tap = 0; tap < 2; ++tap)
#pragma unroll
      for (int mt = 0; mt < 2; ++mt)
#pragma unroll
        for (int ntl = 0; ntl < 2; ++ntl) {
          f32x4 z = {0.f, 0.f, 0.f, 0.f};
          acc[tap][mt][ntl] = z;
        }
#pragma unroll
    for (int tap = 0; tap < 2; ++tap)
#pragma unroll
      for (int mt = 0; mt < 2; ++mt)
#pragma unroll
        for (int ntl = 0; ntl < 2; ++ntl)
#pragma unroll
          for (int ks = 0; ks < 2; ++ks)
            acc[tap][mt][ntl] = __builtin_amdgcn_mfma_f32_16x16x32_f16(
                Xf[mt][ks], Wf[tap][ntl][ks], acc[tap][mt][ntl], 0, 0, 0);

    // scatter: D col=lane&15 -> chan ntl*16+r; row=mt*16+4g+q -> obj
#pragma unroll
    for (int tap = 0; tap < 2; ++tap)
#pragma unroll
      for (int mt = 0; mt < 2; ++mt)
#pragma unroll
        for (int ntl = 0; ntl < 2; ++ntl) {
          const int cl = ntl * 16 + r;
          const int row0 = mt * 16 + g * 4;
          const float badd = (tap == 0) ? cbv[ntl] : 0.f;
#pragma unroll
          for (int q = 0; q < 4; ++q)
            if (row0 + q < NOBJ)
              abp[wv][tap][row0 + q][cl][s] = f2h_s(acc[tap][mt][ntl][q] + badd);
        }
  }
  // same-wave LDS RAW ordered by lgkmcnt; abp wave-private -> no barrier

  // ---- packed pairwise: lane = (h = lane>>5, c = lane&31) ----
  const int hh = lane >> 5, c = lane & 31;
  const uint* abu = reinterpret_cast<const uint*>(&abp[wv][0][0][0][0]);
  // uint layout: [tap][obj][chan]; tap stride 26*33=858, obj stride 33
  f16x2 Apk[NOBJ], Bpk[NOBJ];  // Bpk[j] = B[j + hh] (shift folded into load)
#pragma unroll
  for (int i = 0; i < NOBJ; ++i) {
    uint a = abu[i * 33 + c];
    uint b = abu[858 + (i + hh) * 33 + c];
    Apk[i] = *reinterpret_cast<f16x2*>(&a);
    Bpk[i] = *reinterpret_cast<f16x2*>(&b);
  }
  const f16x2 zz = {(_Float16)0.f, (_Float16)0.f};
  float hacc0 = 0.f, hacc1 = 0.f;
  // lane-half hh handles d = 2*dv + 1 + hh, dv = 0..11; term i uses
  // Bpk[i + 2dv + 1] = B[i + d]. Uniform trip count; h=1's last term hits
  // the -6e4 pad -> relu 0.
#pragma unroll
  for (int dv = 0; dv < 12; ++dv) {
    f16x2 sdp = zz;
#pragma unroll
    for (int i = 0; i <= 23 - 2 * dv; ++i) {
      f16x2 tt = Apk[i] + Bpk[i + 2 * dv + 1];
      sdp += pk_max(tt, zz);
    }
    const float w = hh ? (1.0f / (float)(23 - 2 * dv)) : (1.0f / (float)(24 - 2 * dv));
    hacc0 = __builtin_fmaf((float)sdp[0], w, hacc0);
    hacc1 = __builtin_fmaf((float)sdp[1], w, hacc1);
  }
  hacc0 += __shfl_xor(hacc0, 32);
  hacc1 += __shfl_xor(hacc1, 32);

  const float sc = 1.0f / (float)(NOBJ - 1);
  if (hh == 0)
    h0[(size_t)n0 * 256 + chbase + c] = f2h_s(hacc0 * sc);
  else
    h0[(size_t)(n0 + 1) * 256 + chbase + c] = f2h_s(hacc1 * sc);
}

// ---------------------------------------------------------------------------
// K2 (R19 verbatim): full 3-layer MLP, single f16, 64 blocks x 1024 threads
// (16 waves = 4/SIMD). Wave wv owns one 16-col tile; Hs f16 ping-pong in LDS.
// ---------------------------------------------------------------------------
__global__ __launch_bounds__(1024, 4) void mlp_fused(
    const short* __restrict__ h0,   // (1024,256) f16 bits
    const short* __restrict__ wfm,  // fragment-linear f16 weights
    const float* __restrict__ b1, const float* __restrict__ b2,
    const float* __restrict__ b3,
    float* __restrict__ out)        // (1024, 10)
{
  __shared__ short Hs[2][16][272];  // [pp][row][k] f16 bits, 17408 B
  const int t = threadIdx.x, lane = t & 63, wv = t >> 6;
  const int r = lane & 15, g = lane >> 4;
  const int m0 = blockIdx.x * 16;

  {
    const s16x4 v = reinterpret_cast<const s16x4*>(h0 + (size_t)m0 * 256)[t];
    *reinterpret_cast<s16x4*>(&Hs[0][t >> 6][(t & 63) * 4]) = v;
  }
  __syncthreads();

  int pp = 0;
  const float* bias[2] = {b1, b2};
#pragma unroll
  for (int L = 0; L < 2; ++L) {
    const short* wl = wfm + L * 65536;

    f16x8 bfr[8];
#pragma unroll
    for (int ks = 0; ks < 8; ++ks)
      bfr[ks] = *reinterpret_cast<const f16x8*>(wl + ((wv * 8 + ks) << 9) + lane * 8);

    const float bv = bias[L][wv * 16 + r];
    f32x4 acc = {bv, bv, bv, bv};
#pragma unroll
    for (int ks = 0; ks < 8; ++ks) {
      const f16x8 afr = *reinterpret_cast<const f16x8*>(&Hs[pp][r][ks * 32 + g * 8]);
      acc = __builtin_amdgcn_mfma_f32_16x16x32_f16(afr, bfr[ks], acc, 0, 0, 0);
    }

    const int col = wv * 16 + r;
#pragma unroll
    for (int q = 0; q < 4; ++q)
      Hs[pp ^ 1][4 * g + q][col] = f2h_s(fmaxf(acc[q], 0.f));
    __syncthreads();
    pp ^= 1;
  }

  // layer 3: one 16x16 tile (cols 10..15 zero-padded), wave 0 only
  if (wv == 0) {
    const float bv = (r < 10) ? b3[r] : 0.f;
    f32x4 acc = {bv, bv, bv, bv};
#pragma unroll
    for (int ks = 0; ks < 8; ++ks) {
      const f16x8 afr = *reinterpret_cast<const f16x8*>(&Hs[pp][r][ks * 32 + g * 8]);
      const f16x8 bfr = *reinterpret_cast<const f16x8*>(wfm + 131072 + (ks << 9) + lane * 8);
      acc = __builtin_amdgcn_mfma_f32_16x16x32_f16(afr, bfr, acc, 0, 0, 0);
    }
    if (r < 10) {
#pragma unroll
      for (int q = 0; q < 4; ++q)
        out[(size_t)(m0 + 4 * g + q) * 10 + r] = acc[q];
    }
  }
}

extern "C" void kernel_launch(void* const* d_in, const int* in_sizes, int n_in,
                              void* d_out, int out_size, void* d_ws, size_t ws_size,
                              hipStream_t stream) {
  const float* x   = (const float*)d_in[0];
  const float* cw0 = (const float*)d_in[1];
  const float* cw1 = (const float*)d_in[2];
  const float* cb  = (const float*)d_in[3];
  const float* w1  = (const float*)d_in[4];
  const float* b1  = (const float*)d_in[5];
  const float* w2  = (const float*)d_in[6];
  const float* b2  = (const float*)d_in[7];
  const float* w3  = (const float*)d_in[8];
  const float* b3  = (const float*)d_in[9];
  float* out = (float*)d_out;

  short* h0  = (short*)d_ws;           // 512 KB f16
  short* wfm = h0 + 262144;            // 264 KB f16 frag-linear weights

  conv_prep_kernel<<<1024, 256, 0, stream>>>(x, cw0, cw1, cb, w1, w2, w3, h0, wfm);
  mlp_fused<<<64, 1024, 0, stream>>>(h0, wfm, b1, b2, b3, out);
}

// Round 22
// 26.354 us; speedup vs baseline: 7.0060x; 1.1255x over previous
//
#include <hip/hip_runtime.h>
#include <hip/hip_bf16.h>

#define NOBJ 25

typedef _Float16 f16x8 __attribute__((ext_vector_type(8)));
typedef _Float16 f16x2 __attribute__((ext_vector_type(2)));
typedef short s16x4 __attribute__((ext_vector_type(4)));
typedef float f32x4 __attribute__((ext_vector_type(4)));
typedef unsigned int uint;

__device__ __forceinline__ short f2h_s(float f) {
  _Float16 h = (_Float16)f;   // single v_cvt_f16_f32 (RTN)
  return *reinterpret_cast<short*>(&h);
}

// ---------------------------------------------------------------------------
// K1: R19 structure (512 blocks x 256 thr, 2/CU; inline prep share; xs-staged
// coalesced x; f16 MFMA; wave = 64 channels, 2 samples). ONE change vs R19:
// the ab round-trip is PACKED per-sample f16 -> pairwise runs on f16x2
// (v_pk_add/v_pk_max via native vector ops), halving the 1850-instr scalar
// chain and the ds_read count. Scatter writes short halves into
// [tap][obj][chan][sample]; reads are one uint per element (conflict-free,
// stride-1 lanes).
// ---------------------------------------------------------------------------
__global__ __launch_bounds__(256, 2) void conv_prep_kernel(
    const float* __restrict__ x,    // (1024, 25*64)
    const float* __restrict__ cw0,  // (256, 64)
    const float* __restrict__ cw1,  // (256, 64)
    const float* __restrict__ cb,   // (256)
    const float* __restrict__ w1, const float* __restrict__ w2,
    const float* __restrict__ w3,
    short* __restrict__ h0,         // (1024, 256) f16 bits
    short* __restrict__ wfm)        // 135168 shorts, fragment-linear f16
{
  __shared__ short xs[2][32][72];            // 9216 B (f16 bits)
  __shared__ short abp[4][2][NOBJ][66][2];   // [wave][tap][obj][chan][sample] 52800 B

  const int t = threadIdx.x;
  const int lane = t & 63;
  const int wv = t >> 6;
  const int r = lane & 15;
  const int g = lane >> 4;
  const int n0 = blockIdx.x * 2;

  // ---- x staging first: cold HBM misses issued before anything else ----
  for (int s = 0; s < 2; ++s) {
    const float4* xg = reinterpret_cast<const float4*>(x + (size_t)(n0 + s) * (NOBJ * 64));
    for (int i = t; i < 400; i += 256) {
      float4 v = xg[i];
      s16x4 p;
      p.x = f2h_s(v.x); p.y = f2h_s(v.y); p.z = f2h_s(v.z); p.w = f2h_s(v.w);
      *reinterpret_cast<s16x4*>(&xs[s][i >> 4][(i & 15) * 4]) = p;
    }
  }

  // ---- inline prep share (single f16, fragment-linear) ----
  for (int j = blockIdx.x * 256 + t; j < 135168; j += 512 * 256) {
    const float* w; int f, nt;
    const bool isw3 = (j >= 131072);
    if (!isw3) {
      w = (j >> 16) ? w2 : w1;
      f = j & 65535;
      nt = f >> 12;
    } else {
      f = j - 131072;  // 0..4095
      w = w3;
      nt = 0;
    }
    const int ks = (f >> 9) & 7;
    const int l  = (f >> 3) & 63;
    const int jj = f & 7;
    const int col = nt * 16 + (l & 15);
    const int k   = ks * 32 + (l >> 4) * 8 + jj;
    const float v = (isw3 && col >= 10) ? 0.f : w[col * 256 + k];
    wfm[j] = f2h_s(v);
  }

  // ---- conv W fragments (f16) ----
  f16x8 Wf[2][4][2];  // [tap][ntile][kstep]
#pragma unroll
  for (int tap = 0; tap < 2; ++tap) {
    const float* wsrc = tap ? cw1 : cw0;
#pragma unroll
    for (int ntl = 0; ntl < 4; ++ntl)
#pragma unroll
      for (int ks = 0; ks < 2; ++ks) {
        const int ch = wv * 64 + ntl * 16 + r;
        const float* p = wsrc + ch * 64 + ks * 32 + g * 8;
        const float4 a = *reinterpret_cast<const float4*>(p);
        const float4 b = *reinterpret_cast<const float4*>(p + 4);
        f16x8 fr;
        fr[0] = (_Float16)a.x; fr[1] = (_Float16)a.y; fr[2] = (_Float16)a.z; fr[3] = (_Float16)a.w;
        fr[4] = (_Float16)b.x; fr[5] = (_Float16)b.y; fr[6] = (_Float16)b.z; fr[7] = (_Float16)b.w;
        Wf[tap][ntl][ks] = fr;
      }
  }
  float cbv[4];
#pragma unroll
  for (int ntl = 0; ntl < 4; ++ntl) cbv[ntl] = cb[wv * 64 + ntl * 16 + r];

  __syncthreads();

  // ---- per sample: MFMA + packed-half scatter ----
  for (int s = 0; s < 2; ++s) {
    f16x8 Xf[2][2];  // rows 25..31 garbage, outputs unread
#pragma unroll
    for (int mt = 0; mt < 2; ++mt)
#pragma unroll
      for (int ks = 0; ks < 2; ++ks)
        Xf[mt][ks] = *reinterpret_cast<const f16x8*>(&xs[s][mt * 16 + r][ks * 32 + g * 8]);

    f32x4 acc[2][2][4];  // [tap][mtile][ntile]
#pragma unroll
    for (int tap = 0; tap < 2; ++tap)
#pragma unroll
      for (int mt = 0; mt < 2; ++mt)
#pragma unroll
        for (int ntl = 0; ntl < 4; ++ntl) {
          f32x4 z = {0.f, 0.f, 0.f, 0.f};
          acc[tap][mt][ntl] = z;
        }

#pragma unroll
    for (int tap = 0; tap < 2; ++tap)
#pragma unroll
      for (int mt = 0; mt < 2; ++mt)
#pragma unroll
        for (int ntl = 0; ntl < 4; ++ntl)
#pragma unroll
          for (int ks = 0; ks < 2; ++ks)
            acc[tap][mt][ntl] = __builtin_amdgcn_mfma_f32_16x16x32_f16(
                Xf[mt][ks], Wf[tap][ntl][ks], acc[tap][mt][ntl], 0, 0, 0);

    // scatter f16 half into packed [obj][chan][sample]
#pragma unroll
    for (int tap = 0; tap < 2; ++tap)
#pragma unroll
      for (int mt = 0; mt < 2; ++mt)
#pragma unroll
        for (int ntl = 0; ntl < 4; ++ntl) {
          const int cl = ntl * 16 + r;
          const int row0 = mt * 16 + g * 4;
          const float badd = (tap == 0) ? cbv[ntl] : 0.f;
#pragma unroll
          for (int q = 0; q < 4; ++q)
            if (row0 + q < NOBJ)
              abp[wv][tap][row0 + q][cl][s] = f2h_s(acc[tap][mt][ntl][q] + badd);
        }
  }
  // same-wave LDS RAW ordered by lgkmcnt; abp wave-private -> no barrier

  // ---- packed pairwise: lane = channel (both samples per lane) ----
  const uint* abu = reinterpret_cast<const uint*>(&abp[wv][0][0][0][0]);
  // uint layout: [tap][obj][chan66]; tap stride 25*66=1650, obj stride 66
  f16x2 Apk[NOBJ], Bpk[NOBJ];
#pragma unroll
  for (int i = 0; i < NOBJ; ++i) {
    uint a = abu[i * 66 + lane];
    uint b = abu[1650 + i * 66 + lane];
    Apk[i] = *reinterpret_cast<f16x2*>(&a);
    Bpk[i] = *reinterpret_cast<f16x2*>(&b);
  }
  const f16x2 zz = {(_Float16)0.f, (_Float16)0.f};
  float hacc0 = 0.f, hacc1 = 0.f;
#pragma unroll
  for (int d = 1; d < NOBJ; ++d) {
    f16x2 sdp = zz;
#pragma unroll
    for (int i = 0; i + d < NOBJ; ++i)
      sdp += __builtin_elementwise_max(Apk[i] + Bpk[i + d], zz);
    const float w = 1.0f / (float)(NOBJ - d);
    hacc0 = __builtin_fmaf((float)sdp[0], w, hacc0);
    hacc1 = __builtin_fmaf((float)sdp[1], w, hacc1);
  }
  const float sc = 1.0f / (float)(NOBJ - 1);
  h0[(size_t)n0 * 256 + t]       = f2h_s(hacc0 * sc);
  h0[(size_t)(n0 + 1) * 256 + t] = f2h_s(hacc1 * sc);
}

// ---------------------------------------------------------------------------
// K2 (R19 verbatim): full 3-layer MLP, single f16, 64 blocks x 1024 threads
// (16 waves = 4/SIMD). Wave wv owns one 16-col tile; Hs f16 ping-pong in LDS.
// ---------------------------------------------------------------------------
__global__ __launch_bounds__(1024, 4) void mlp_fused(
    const short* __restrict__ h0,   // (1024,256) f16 bits
    const short* __restrict__ wfm,  // fragment-linear f16 weights
    const float* __restrict__ b1, const float* __restrict__ b2,
    const float* __restrict__ b3,
    float* __restrict__ out)        // (1024, 10)
{
  __shared__ short Hs[2][16][272];  // [pp][row][k] f16 bits, 17408 B
  const int t = threadIdx.x, lane = t & 63, wv = t >> 6;
  const int r = lane & 15, g = lane >> 4;
  const int m0 = blockIdx.x * 16;

  {
    const s16x4 v = reinterpret_cast<const s16x4*>(h0 + (size_t)m0 * 256)[t];
    *reinterpret_cast<s16x4*>(&Hs[0][t >> 6][(t & 63) * 4]) = v;
  }
  __syncthreads();

  int pp = 0;
  const float* bias[2] = {b1, b2};
#pragma unroll
  for (int L = 0; L < 2; ++L) {
    const short* wl = wfm + L * 65536;

    f16x8 bfr[8];
#pragma unroll
    for (int ks = 0; ks < 8; ++ks)
      bfr[ks] = *reinterpret_cast<const f16x8*>(wl + ((wv * 8 + ks) << 9) + lane * 8);

    const float bv = bias[L][wv * 16 + r];
    f32x4 acc = {bv, bv, bv, bv};
#pragma unroll
    for (int ks = 0; ks < 8; ++ks) {
      const f16x8 afr = *reinterpret_cast<const f16x8*>(&Hs[pp][r][ks * 32 + g * 8]);
      acc = __builtin_amdgcn_mfma_f32_16x16x32_f16(afr, bfr[ks], acc, 0, 0, 0);
    }

    const int col = wv * 16 + r;
#pragma unroll
    for (int q = 0; q < 4; ++q)
      Hs[pp ^ 1][4 * g + q][col] = f2h_s(fmaxf(acc[q], 0.f));
    __syncthreads();
    pp ^= 1;
  }

  // layer 3: one 16x16 tile (cols 10..15 zero-padded), wave 0 only
  if (wv == 0) {
    const float bv = (r < 10) ? b3[r] : 0.f;
    f32x4 acc = {bv, bv, bv, bv};
#pragma unroll
    for (int ks = 0; ks < 8; ++ks) {
      const f16x8 afr = *reinterpret_cast<const f16x8*>(&Hs[pp][r][ks * 32 + g * 8]);
      const f16x8 bfr = *reinterpret_cast<const f16x8*>(wfm + 131072 + (ks << 9) + lane * 8);
      acc = __builtin_amdgcn_mfma_f32_16x16x32_f16(afr, bfr, acc, 0, 0, 0);
    }
    if (r < 10) {
#pragma unroll
      for (int q = 0; q < 4; ++q)
        out[(size_t)(m0 + 4 * g + q) * 10 + r] = acc[q];
    }
  }
}

extern "C" void kernel_launch(void* const* d_in, const int* in_sizes, int n_in,
                              void* d_out, int out_size, void* d_ws, size_t ws_size,
                              hipStream_t stream) {
  const float* x   = (const float*)d_in[0];
  const float* cw0 = (const float*)d_in[1];
  const float* cw1 = (const float*)d_in[2];
  const float* cb  = (const float*)d_in[3];
  const float* w1  = (const float*)d_in[4];
  const float* b1  = (const float*)d_in[5];
  const float* w2  = (const float*)d_in[6];
  const float* b2  = (const float*)d_in[7];
  const float* w3  = (const float*)d_in[8];
  const float* b3  = (const float*)d_in[9];
  float* out = (float*)d_out;

  short* h0  = (short*)d_ws;           // 512 KB f16
  short* wfm = h0 + 262144;            // 264 KB f16 frag-linear weights

  conv_prep_kernel<<<512, 256, 0, stream>>>(x, cw0, cw1, cb, w1, w2, w3, h0, wfm);
  mlp_fused<<<64, 1024, 0, stream>>>(h0, wfm, b1, b2, b3, out);
}

// Round 23
// 25.619 us; speedup vs baseline: 7.2069x; 1.0287x over previous
//
#include <hip/hip_runtime.h>
#include <hip/hip_bf16.h>

#define NOBJ 25

typedef _Float16 f16x8 __attribute__((ext_vector_type(8)));
typedef _Float16 f16x2 __attribute__((ext_vector_type(2)));
typedef short s16x4 __attribute__((ext_vector_type(4)));
typedef float f32x4 __attribute__((ext_vector_type(4)));
typedef unsigned int uint;

__device__ __forceinline__ short f2h_s(float f) {
  _Float16 h = (_Float16)f;   // single v_cvt_f16_f32 (RTN)
  return *reinterpret_cast<short*>(&h);
}

// ---------------------------------------------------------------------------
// K1: R22's packed-f16 conv + d-parity split across lane halves.
// 1024 blocks x 256 thr, launch_bounds(256,2) (256-VGPR budget -- the R21
// regression was the 128-cap spilling Apk/Bpk; LDS 36.7KB keeps 2 blocks/CU,
// 1024 slots = one residency round).
// Block cbid: samples n0=(cbid>>1)*2..+1; channels (cbid&1)*128 + wv*32.
// Wave = 32 channels, samples packed f16x2. Pairwise: lane = (hh=lane>>5,
// c=lane&31); half hh covers d = 2dv+1+hh (dv=0..11); Bpk[j]=B[j+hh] folds
// the shift into the LDS load (all reg indices static); tap1 obj-25 pad row
// = -6e4 so both halves run uniform trips (pad terms relu to 0). Halves
// combine via shfl_xor(32). ~530 packed instr vs R22's ~925.
// ---------------------------------------------------------------------------
__global__ __launch_bounds__(256, 2) void conv_prep_kernel(
    const float* __restrict__ x,    // (1024, 25*64)
    const float* __restrict__ cw0,  // (256, 64)
    const float* __restrict__ cw1,  // (256, 64)
    const float* __restrict__ cb,   // (256)
    const float* __restrict__ w1, const float* __restrict__ w2,
    const float* __restrict__ w3,
    short* __restrict__ h0,         // (1024, 256) f16 bits
    short* __restrict__ wfm)        // 135168 shorts, fragment-linear f16
{
  __shared__ short xs[2][32][72];            // 9216 B (f16 bits)
  __shared__ short abp[4][2][26][33][2];     // [wave][tap][obj+pad][chan][sample] 27456 B

  const int t = threadIdx.x;
  const int lane = t & 63;
  const int wv = t >> 6;
  const int r = lane & 15;
  const int g = lane >> 4;
  const int cbid = blockIdx.x;
  const int n0 = (cbid >> 1) * 2;
  const int chbase = (cbid & 1) * 128 + wv * 32;

  // ---- x staging first: cold HBM misses issued before anything else ----
  for (int s = 0; s < 2; ++s) {
    const float4* xg = reinterpret_cast<const float4*>(x + (size_t)(n0 + s) * (NOBJ * 64));
    for (int i = t; i < 400; i += 256) {
      float4 v = xg[i];
      s16x4 p;
      p.x = f2h_s(v.x); p.y = f2h_s(v.y); p.z = f2h_s(v.z); p.w = f2h_s(v.w);
      *reinterpret_cast<s16x4*>(&xs[s][i >> 4][(i & 15) * 4]) = p;
    }
  }

  // ---- inline prep share (single f16, fragment-linear; <=1 elem/thread) ----
  for (int j = cbid * 256 + t; j < 135168; j += 1024 * 256) {
    const float* w; int f, nt;
    const bool isw3 = (j >= 131072);
    if (!isw3) {
      w = (j >> 16) ? w2 : w1;
      f = j & 65535;
      nt = f >> 12;
    } else {
      f = j - 131072;  // 0..4095
      w = w3;
      nt = 0;
    }
    const int ks = (f >> 9) & 7;
    const int l  = (f >> 3) & 63;
    const int jj = f & 7;
    const int col = nt * 16 + (l & 15);
    const int k   = ks * 32 + (l >> 4) * 8 + jj;
    const float v = (isw3 && col >= 10) ? 0.f : w[col * 256 + k];
    wfm[j] = f2h_s(v);
  }

  // ---- W fragments: 32 channels (2 ntl), both taps ----
  f16x8 Wf[2][2][2];  // [tap][ntl][ks]
#pragma unroll
  for (int tap = 0; tap < 2; ++tap) {
    const float* wsrc = tap ? cw1 : cw0;
#pragma unroll
    for (int ntl = 0; ntl < 2; ++ntl)
#pragma unroll
      for (int ks = 0; ks < 2; ++ks) {
        const float* p = wsrc + (chbase + ntl * 16 + r) * 64 + ks * 32 + g * 8;
        const float4 a = *reinterpret_cast<const float4*>(p);
        const float4 b = *reinterpret_cast<const float4*>(p + 4);
        f16x8 fr;
        fr[0] = (_Float16)a.x; fr[1] = (_Float16)a.y; fr[2] = (_Float16)a.z; fr[3] = (_Float16)a.w;
        fr[4] = (_Float16)b.x; fr[5] = (_Float16)b.y; fr[6] = (_Float16)b.z; fr[7] = (_Float16)b.w;
        Wf[tap][ntl][ks] = fr;
      }
  }
  float cbv[2];
#pragma unroll
  for (int ntl = 0; ntl < 2; ++ntl) cbv[ntl] = cb[chbase + ntl * 16 + r];

  // tap1 pad row (obj 25) = -6e4: relu-dead filler for the hh=1 shifted reads
  if (lane < 32) {
    uint* pr = reinterpret_cast<uint*>(&abp[wv][1][25][0][0]);
    const uint neg = ((uint)(unsigned short)f2h_s(-6.0e4f)) * 0x10001u;
    pr[lane] = neg;  // lanes 0..31 cover the 32 channels (33rd is padding)
  }

  __syncthreads();

  // ---- per sample: MFMA + packed-half scatter ----
#pragma unroll
  for (int s = 0; s < 2; ++s) {
    f16x8 Xf[2][2];  // rows 25..31 garbage, outputs unread
#pragma unroll
    for (int mt = 0; mt < 2; ++mt)
#pragma unroll
      for (int ks = 0; ks < 2; ++ks)
        Xf[mt][ks] = *reinterpret_cast<const f16x8*>(&xs[s][mt * 16 + r][ks * 32 + g * 8]);

    f32x4 acc[2][2][2];  // [tap][mt][ntl]
#pragma unroll
    for (int tap = 0; tap < 2; ++tap)
#pragma unroll
      for (int mt = 0; mt < 2; ++mt)
#pragma unroll
        for (int ntl = 0; ntl < 2; ++ntl) {
          f32x4 z = {0.f, 0.f, 0.f, 0.f};
          acc[tap][mt][ntl] = z;
        }
#pragma unroll
    for (int tap = 0; tap < 2; ++tap)
#pragma unroll
      for (int mt = 0; mt < 2; ++mt)
#pragma unroll
        for (int ntl = 0; ntl < 2; ++ntl)
#pragma unroll
          for (int ks = 0; ks < 2; ++ks)
            acc[tap][mt][ntl] = __builtin_amdgcn_mfma_f32_16x16x32_f16(
                Xf[mt][ks], Wf[tap][ntl][ks], acc[tap][mt][ntl], 0, 0, 0);

    // scatter f16 half into packed [obj][chan][sample]
#pragma unroll
    for (int tap = 0; tap < 2; ++tap)
#pragma unroll
      for (int mt = 0; mt < 2; ++mt)
#pragma unroll
        for (int ntl = 0; ntl < 2; ++ntl) {
          const int cl = ntl * 16 + r;
          const int row0 = mt * 16 + g * 4;
          const float badd = (tap == 0) ? cbv[ntl] : 0.f;
#pragma unroll
          for (int q = 0; q < 4; ++q)
            if (row0 + q < NOBJ)
              abp[wv][tap][row0 + q][cl][s] = f2h_s(acc[tap][mt][ntl][q] + badd);
        }
  }
  // same-wave LDS RAW ordered by lgkmcnt; abp wave-private -> no barrier

  // ---- packed pairwise, d-parity split: lane = (hh, c) ----
  const int hh = lane >> 5, c = lane & 31;
  const uint* abu = reinterpret_cast<const uint*>(&abp[wv][0][0][0][0]);
  // uint layout: [tap][obj26][chan33]; tap stride 26*33=858, obj stride 33
  f16x2 Apk[NOBJ], Bpk[NOBJ + 1];  // Bpk[j] = B[j + hh]
#pragma unroll
  for (int i = 0; i < NOBJ; ++i) {
    uint a = abu[i * 33 + c];
    Apk[i] = *reinterpret_cast<f16x2*>(&a);
  }
#pragma unroll
  for (int j = 0; j < NOBJ + 1; ++j) {
    uint b = abu[858 + (j + hh) * 33 + c];  // j+hh <= 25 -> tap1 rows 0..25
    Bpk[j] = *reinterpret_cast<f16x2*>(&b);
  }
  const f16x2 zz = {(_Float16)0.f, (_Float16)0.f};
  float hacc0 = 0.f, hacc1 = 0.f;
  // half hh covers d = 2*dv + 1 + hh, dv = 0..11; term i uses Bpk[i+2dv+1]
  // = B[i+d]. Uniform trips; hh=1's j=25 reads hit the -6e4 pad -> relu 0.
#pragma unroll
  for (int dv = 0; dv < 12; ++dv) {
    f16x2 sdp = zz;
#pragma unroll
    for (int i = 0; i <= 23 - 2 * dv; ++i)
      sdp += __builtin_elementwise_max(Apk[i] + Bpk[i + 2 * dv + 1], zz);
    const float w = hh ? (1.0f / (float)(23 - 2 * dv)) : (1.0f / (float)(24 - 2 * dv));
    hacc0 = __builtin_fmaf((float)sdp[0], w, hacc0);
    hacc1 = __builtin_fmaf((float)sdp[1], w, hacc1);
  }
  hacc0 += __shfl_xor(hacc0, 32);
  hacc1 += __shfl_xor(hacc1, 32);

  const float sc = 1.0f / (float)(NOBJ - 1);
  h0[(size_t)(n0 + hh) * 256 + chbase + c] = f2h_s((hh ? hacc1 : hacc0) * sc);
}

// ---------------------------------------------------------------------------
// K2 (R19/R22 verbatim): full 3-layer MLP, single f16, 64 blocks x 1024
// threads (16 waves = 4/SIMD). Wave wv owns one 16-col tile; Hs ping-pong.
// ---------------------------------------------------------------------------
__global__ __launch_bounds__(1024, 4) void mlp_fused(
    const short* __restrict__ h0,   // (1024,256) f16 bits
    const short* __restrict__ wfm,  // fragment-linear f16 weights
    const float* __restrict__ b1, const float* __restrict__ b2,
    const float* __restrict__ b3,
    float* __restrict__ out)        // (1024, 10)
{
  __shared__ short Hs[2][16][272];  // [pp][row][k] f16 bits, 17408 B
  const int t = threadIdx.x, lane = t & 63, wv = t >> 6;
  const int r = lane & 15, g = lane >> 4;
  const int m0 = blockIdx.x * 16;

  {
    const s16x4 v = reinterpret_cast<const s16x4*>(h0 + (size_t)m0 * 256)[t];
    *reinterpret_cast<s16x4*>(&Hs[0][t >> 6][(t & 63) * 4]) = v;
  }
  __syncthreads();

  int pp = 0;
  const float* bias[2] = {b1, b2};
#pragma unroll
  for (int L = 0; L < 2; ++L) {
    const short* wl = wfm + L * 65536;

    f16x8 bfr[8];
#pragma unroll
    for (int ks = 0; ks < 8; ++ks)
      bfr[ks] = *reinterpret_cast<const f16x8*>(wl + ((wv * 8 + ks) << 9) + lane * 8);

    const float bv = bias[L][wv * 16 + r];
    f32x4 acc = {bv, bv, bv, bv};
#pragma unroll
    for (int ks = 0; ks < 8; ++ks) {
      const f16x8 afr = *reinterpret_cast<const f16x8*>(&Hs[pp][r][ks * 32 + g * 8]);
      acc = __builtin_amdgcn_mfma_f32_16x16x32_f16(afr, bfr[ks], acc, 0, 0, 0);
    }

    const int col = wv * 16 + r;
#pragma unroll
    for (int q = 0; q < 4; ++q)
      Hs[pp ^ 1][4 * g + q][col] = f2h_s(fmaxf(acc[q], 0.f));
    __syncthreads();
    pp ^= 1;
  }

  // layer 3: one 16x16 tile (cols 10..15 zero-padded), wave 0 only
  if (wv == 0) {
    const float bv = (r < 10) ? b3[r] : 0.f;
    f32x4 acc = {bv, bv, bv, bv};
#pragma unroll
    for (int ks = 0; ks < 8; ++ks) {
      const f16x8 afr = *reinterpret_cast<const f16x8*>(&Hs[pp][r][ks * 32 + g * 8]);
      const f16x8 bfr = *reinterpret_cast<const f16x8*>(wfm + 131072 + (ks << 9) + lane * 8);
      acc = __builtin_amdgcn_mfma_f32_16x16x32_f16(afr, bfr, acc, 0, 0, 0);
    }
    if (r < 10) {
#pragma unroll
      for (int q = 0; q < 4; ++q)
        out[(size_t)(m0 + 4 * g + q) * 10 + r] = acc[q];
    }
  }
}

extern "C" void kernel_launch(void* const* d_in, const int* in_sizes, int n_in,
                              void* d_out, int out_size, void* d_ws, size_t ws_size,
                              hipStream_t stream) {
  const float* x   = (const float*)d_in[0];
  const float* cw0 = (const float*)d_in[1];
  const float* cw1 = (const float*)d_in[2];
  const float* cb  = (const float*)d_in[3];
  const float* w1  = (const float*)d_in[4];
  const float* b1  = (const float*)d_in[5];
  const float* w2  = (const float*)d_in[6];
  const float* b2  = (const float*)d_in[7];
  const float* w3  = (const float*)d_in[8];
  const float* b3  = (const float*)d_in[9];
  float* out = (float*)d_out;

  short* h0  = (short*)d_ws;           // 512 KB f16
  short* wfm = h0 + 262144;            // 264 KB f16 frag-linear weights

  conv_prep_kernel<<<1024, 256, 0, stream>>>(x, cw0, cw1, cb, w1, w2, w3, h0, wfm);
  mlp_fused<<<64, 1024, 0, stream>>>(h0, wfm, b1, b2, b3, out);
}